// Round 1
// baseline (487.479 us; speedup 1.0000x reference)
//
#include <hip/hip_runtime.h>

static constexpr int D   = 64;       // embedding dim (C)
static constexpr int KC  = 1024;     // codebook size
static constexpr int HW  = 4096;     // 64*64
static constexpr long QSZ = 16L*64*64*64; // 4194304 elements per output tensor

// ---------------------------------------------------------------------------
// kernel 0: enorm[k] = sum_c E[k][c]^2   (1024 values into d_ws)
// ---------------------------------------------------------------------------
__global__ void __launch_bounds__(64) enorm_kernel(const float* __restrict__ E,
                                                   float* __restrict__ enorm) {
  const int k = blockIdx.x;
  const int c = threadIdx.x;
  float v = E[k * D + c];
  float s = v * v;
#pragma unroll
  for (int off = 32; off; off >>= 1) s += __shfl_down(s, off, 64);
  if (c == 0) enorm[k] = s;
}

// ---------------------------------------------------------------------------
// main kernel: one block (256 thr = 4 waves) per (b,h); 64 rows (w = lane).
// Phase 1: per-lane argmin over a K/4 chunk per wave (f held in 64 VGPRs,
//          E rows read via wave-uniform addresses -> scalar loads).
// Phase 2: cross-wave argmin reduce in LDS.
// Phase 3: coalesced output of quantized / latents / quantized_latents via
//          padded LDS transpose tiles.
// ---------------------------------------------------------------------------
__global__ void __launch_bounds__(256) vq_kernel(const float* __restrict__ X,
                                                 const float* __restrict__ E,
                                                 const float* __restrict__ enorm,
                                                 float* __restrict__ out) {
  const int bh   = blockIdx.x;      // 0..1023
  const int b    = bh >> 6;
  const int h    = bh & 63;
  const int tid  = threadIdx.x;
  const int wave = tid >> 6;
  const int lane = tid & 63;

  // X[b][c][h][w] = xbase[c*HW + w]
  const float* __restrict__ xbase = X + (size_t)b * (D * HW) + h * 64;

  // ---- load this lane's row vector f (row w == lane), coalesced per c ----
  float f[D];
#pragma unroll
  for (int c = 0; c < D; ++c) f[c] = xbase[c * HW + lane];

  // ---- phase 1: scan this wave's K-chunk ----
  float best = 3.4e38f;
  int   bidx = 0;
  const int k0 = wave * (KC / 4);
  for (int k = k0; k < k0 + (KC / 4); ++k) {
    const float* __restrict__ e = E + k * D;   // wave-uniform address
    float a0 = 0.f, a1 = 0.f, a2 = 0.f, a3 = 0.f;
#pragma unroll
    for (int c = 0; c < D; c += 4) {
      a0 = fmaf(f[c + 0], e[c + 0], a0);
      a1 = fmaf(f[c + 1], e[c + 1], a1);
      a2 = fmaf(f[c + 2], e[c + 2], a2);
      a3 = fmaf(f[c + 3], e[c + 3], a3);
    }
    const float score = enorm[k] - 2.0f * ((a0 + a1) + (a2 + a3));
    if (score < best) { best = score; bidx = k; }  // strict < keeps earliest k
  }

  __shared__ float sc_s[4][64];
  __shared__ int   id_s[4][64];
  __shared__ int   idx_s[64];
  __shared__ float tile[64 * 65];  // tile[c*65+w] = X[b][c][h][w]  (padded)
  __shared__ float eq[64 * 65];    // eq[w*65+c]   = E[idx[w]][c]   (padded)

  sc_s[wave][lane] = best;
  id_s[wave][lane] = bidx;
  if (wave == 0) {
#pragma unroll
    for (int c = 0; c < D; ++c) tile[c * 65 + lane] = f[c];
  }
  __syncthreads();

  // ---- phase 2: reduce across the 4 wave-chunks (ascending chunk order) ----
  if (tid < 64) {
    float bs = sc_s[0][tid];
    int   bi = id_s[0][tid];
#pragma unroll
    for (int wv = 1; wv < 4; ++wv) {
      const float s2 = sc_s[wv][tid];
      const int   i2 = id_s[wv][tid];
      if (s2 < bs) { bs = s2; bi = i2; }  // strict <: lower chunk wins ties
    }
    idx_s[tid] = bi;
  }
  __syncthreads();

  // ---- phase 3: outputs ----
  float* __restrict__ qout = out;                    // [B,C,H,W]
  float* __restrict__ lat  = out + QSZ;              // [B,H,W,C]
  float* __restrict__ ql   = out + 2 * QSZ;          // [B,H,W,C]
  const size_t n0 = (size_t)bh * 64;

  // enum B (w-major): per 64-lane group w fixed, c = lane -> all coalesced
#pragma unroll
  for (int i = 0; i < 16; ++i) {
    const int e_ = i * 256 + tid;
    const int w = e_ >> 6, c = e_ & 63;
    const float q = E[idx_s[w] * D + c];    // coalesced gather (w uniform/group)
    eq[w * 65 + c] = q;
    ql[(n0 + w) * D + c]  = q;
    lat[(n0 + w) * D + c] = tile[c * 65 + w];  // stride-65 LDS read: no conflict
  }
  __syncthreads();

  // enum A (c-major): per 64-lane group c fixed, w = lane -> coalesced [b][c][h][w]
  float* __restrict__ qb = qout + (size_t)b * (D * HW) + h * 64;
#pragma unroll
  for (int i = 0; i < 16; ++i) {
    const int e_ = i * 256 + tid;
    const int c = e_ >> 6, w = e_ & 63;
    qb[c * HW + w] = eq[w * 65 + c];           // stride-65 LDS read: no conflict
  }
}

extern "C" void kernel_launch(void* const* d_in, const int* in_sizes, int n_in,
                              void* d_out, int out_size, void* d_ws, size_t ws_size,
                              hipStream_t stream) {
  const float* X = (const float*)d_in[0];   // inputs  [16,64,64,64] fp32
  const float* E = (const float*)d_in[1];   // embeddings [1024,64] fp32
  float* out   = (float*)d_out;
  float* enorm = (float*)d_ws;              // 1024 floats of scratch

  enorm_kernel<<<KC, 64, 0, stream>>>(E, enorm);
  vq_kernel<<<1024, 256, 0, stream>>>(X, E, enorm, out);
}

// Round 2
// 96.405 us; speedup vs baseline: 5.0566x; 5.0566x over previous
//
#include <hip/hip_runtime.h>

static constexpr int  D   = 64;        // embedding dim (C)
static constexpr int  KC  = 1024;      // codebook size
static constexpr int  HW  = 4096;      // 64*64
static constexpr long QSZ = 16L*64*64*64;  // elems per output tensor
static constexpr float DELTA = 0.02f;  // bf16-split score error bound is ~2e-3; 10x margin

// ---- d_ws layout (bytes) ----
static constexpr size_t WS_ENORM = 0;        // f32[1024]
static constexpr size_t WS_EHI   = 4096;     // u16[65536] bf16 hi
static constexpr size_t WS_ELO   = 135168;   // u16[65536] bf16 lo
static constexpr size_t WS_CNT   = 266240;   // i32 flagged-row count
static constexpr size_t WS_LIST  = 266244;   // i32[65536] flagged rows
static constexpr size_t WS_NEED  = 528388;

typedef __attribute__((ext_vector_type(8))) short s16x8;   // 8 bf16 (4 VGPR)
typedef __attribute__((ext_vector_type(4))) float f32x4;   // MFMA C/D

__device__ __forceinline__ unsigned short f2bf(float x) {  // RN-even, matches HW cvt
  union { float f; unsigned u; } v; v.f = x;
  unsigned r = v.u + 0x7FFFu + ((v.u >> 16) & 1u);
  return (unsigned short)(r >> 16);
}
__device__ __forceinline__ float bf2f(unsigned short h) {
  union { unsigned u; float f; } v; v.u = ((unsigned)h) << 16; return v.f;
}

// ---------------------------------------------------------------------------
// prep: enorm[k], bf16 hi/lo split of E, zero flag counter
// ---------------------------------------------------------------------------
__global__ void __launch_bounds__(64) prep_kernel(const float* __restrict__ E,
                                                  float* __restrict__ enorm,
                                                  unsigned short* __restrict__ Ehi,
                                                  unsigned short* __restrict__ Elo,
                                                  int* __restrict__ cnt) {
  const int k = blockIdx.x, c = threadIdx.x;
  if (k == 0 && c == 0) *cnt = 0;
  const float v = E[k * D + c];
  const unsigned short hb = f2bf(v);
  const unsigned short lb = f2bf(v - bf2f(hb));
  Ehi[k * D + c] = hb;
  Elo[k * D + c] = lb;
  float s = v * v;
#pragma unroll
  for (int off = 32; off; off >>= 1) s += __shfl_down(s, off, 64);
  if (c == 0) enorm[k] = s;
}

// ---------------------------------------------------------------------------
// main MFMA kernel: 256 blocks x 256 thr; block = 256 rows (4 bh), wave = 64 rows.
// S = F.E^T via 3-term bf16 split on mfma_f32_16x16x32_bf16; per-row top-2
// tracking; rows with gap < DELTA flagged for exact fp32 recheck.
// ---------------------------------------------------------------------------
__global__ void __launch_bounds__(256) vq_mfma_kernel(const float* __restrict__ X,
                                                      const float* __restrict__ E,
                                                      const float* __restrict__ enorm,
                                                      const unsigned short* __restrict__ Ehi,
                                                      const unsigned short* __restrict__ Elo,
                                                      float* __restrict__ out,
                                                      int* __restrict__ cnt,
                                                      int* __restrict__ list) {
  __shared__ float Xt[256][68];   // fp32 rows (68: 16B-aligned rows for float4 reads)
  __shared__ float eq[64][65];
  __shared__ int   idx_s[256];

  const int tid  = threadIdx.x;
  const int wave = tid >> 6;
  const int lane = tid & 63;
  const int b    = blockIdx.x >> 4;          // 4 bh per block, same b
  const int h0   = (blockIdx.x & 15) * 4;

  // ---- phase A: stage block's 256x64 X-slice, transposed to row-major ----
  const float* __restrict__ xbase = X + (size_t)b * (D * HW) + h0 * 64;
#pragma unroll 4
  for (int c = 0; c < D; ++c)
    Xt[tid][c] = xbase[c * HW + tid];   // coalesced read; LDS write 2-way (free)
  __syncthreads();

  // ---- phase B: A-fragments (bf16 hi/lo) in registers, once per block ----
  s16x8 ah[4][2], al[4][2];
#pragma unroll
  for (int mi = 0; mi < 4; ++mi) {
    const int row = wave * 64 + mi * 16 + (lane & 15);
#pragma unroll
    for (int ks = 0; ks < 2; ++ks) {
      const int k0 = ks * 32 + (lane >> 4) * 8;
      const float* xp = &Xt[row][k0];
      s16x8 h, l;
#pragma unroll
      for (int j = 0; j < 8; ++j) {
        const float x = xp[j];
        const unsigned short hb = f2bf(x);
        h[j] = (short)hb;
        l[j] = (short)f2bf(x - bf2f(hb));
      }
      ah[mi][ks] = h; al[mi][ks] = l;
    }
  }

  // ---- phase C: sweep codebook in 16 chunks of 64 cols ----
  float b1[4][4], b2[4][4]; int i1[4][4];
#pragma unroll
  for (int mi = 0; mi < 4; ++mi)
#pragma unroll
    for (int r = 0; r < 4; ++r) { b1[mi][r] = 3.4e38f; b2[mi][r] = 3.4e38f; i1[mi][r] = 0; }

  for (int chunk = 0; chunk < 16; ++chunk) {
    const int nc = chunk * 64;
#pragma unroll
    for (int ni = 0; ni < 4; ++ni) {
      const int col = nc + ni * 16 + (lane & 15);
      const int k0a = (lane >> 4) * 8;
      const s16x8 bh0 = *(const s16x8*)(Ehi + (size_t)col * D + k0a);
      const s16x8 bh1 = *(const s16x8*)(Ehi + (size_t)col * D + 32 + k0a);
      const s16x8 bl0 = *(const s16x8*)(Elo + (size_t)col * D + k0a);
      const s16x8 bl1 = *(const s16x8*)(Elo + (size_t)col * D + 32 + k0a);
      const float en = enorm[col];
#pragma unroll
      for (int mi = 0; mi < 4; ++mi) {
        f32x4 acc = {0.f, 0.f, 0.f, 0.f};
        acc = __builtin_amdgcn_mfma_f32_16x16x32_bf16(ah[mi][0], bh0, acc, 0, 0, 0);
        acc = __builtin_amdgcn_mfma_f32_16x16x32_bf16(ah[mi][0], bl0, acc, 0, 0, 0);
        acc = __builtin_amdgcn_mfma_f32_16x16x32_bf16(al[mi][0], bh0, acc, 0, 0, 0);
        acc = __builtin_amdgcn_mfma_f32_16x16x32_bf16(ah[mi][1], bh1, acc, 0, 0, 0);
        acc = __builtin_amdgcn_mfma_f32_16x16x32_bf16(ah[mi][1], bl1, acc, 0, 0, 0);
        acc = __builtin_amdgcn_mfma_f32_16x16x32_bf16(al[mi][1], bh1, acc, 0, 0, 0);
#pragma unroll
        for (int r = 0; r < 4; ++r) {
          const float s  = fmaf(-2.f, acc[r], en);
          const float n2 = fminf(b2[mi][r], fmaxf(b1[mi][r], s));
          const bool  lt = s < b1[mi][r];
          b1[mi][r] = fminf(b1[mi][r], s);
          i1[mi][r] = lt ? col : i1[mi][r];
          b2[mi][r] = n2;
        }
      }
    }
  }

  // ---- phase D: merge top-2 across the 16 col-lanes; flag near-ties ----
#pragma unroll
  for (int mi = 0; mi < 4; ++mi) {
#pragma unroll
    for (int r = 0; r < 4; ++r) {
      float B1 = b1[mi][r], B2 = b2[mi][r]; int I1 = i1[mi][r];
#pragma unroll
      for (int m = 1; m < 16; m <<= 1) {
        const float o1 = __shfl_xor(B1, m, 64);
        const float o2 = __shfl_xor(B2, m, 64);
        const int   oi = __shfl_xor(I1, m, 64);
        const float n2 = fminf(fminf(B2, o2), fmaxf(B1, o1));
        if (o1 < B1) { B1 = o1; I1 = oi; }
        B2 = n2;
      }
      if ((lane & 15) == 0) {
        const int rl = wave * 64 + mi * 16 + (lane >> 4) * 4 + r;
        idx_s[rl] = I1;
        if (B2 - B1 < DELTA) {                 // ties / near-ties -> exact path
          const int pos = atomicAdd(cnt, 1);
          list[pos] = blockIdx.x * 256 + rl;
        }
      }
    }
  }
  __syncthreads();

  // ---- phase E: outputs (coalesced via LDS transpose tiles) ----
  float* __restrict__ qout = out;
  float* __restrict__ lat  = out + QSZ;
  float* __restrict__ ql   = out + 2 * QSZ;
  const size_t n0b = (size_t)blockIdx.x * 256;

  for (int ch = 0; ch < 4; ++ch) {
    const size_t n0 = n0b + ch * 64;
#pragma unroll
    for (int i = 0; i < 16; ++i) {
      const int e_ = i * 256 + tid;
      const int w = e_ >> 6, c = e_ & 63;
      const float q = E[idx_s[ch * 64 + w] * D + c];  // coalesced gather
      eq[w][c] = q;
      ql[(n0 + w) * D + c]  = q;
      lat[(n0 + w) * D + c] = Xt[ch * 64 + w][c];
    }
    __syncthreads();
    float* __restrict__ qb = qout + (size_t)b * (D * HW) + (h0 + ch) * 64;
#pragma unroll
    for (int i = 0; i < 16; ++i) {
      const int e_ = i * 256 + tid;
      const int c = e_ >> 6, w = e_ & 63;
      qb[c * HW + w] = eq[w][c];
    }
    __syncthreads();
  }
}

// ---------------------------------------------------------------------------
// exact fp32 recheck for flagged rows (reproduces R1's passing arithmetic,
// incl. lowest-index tie-break). One wave per row, grid-stride over list.
// ---------------------------------------------------------------------------
__global__ void __launch_bounds__(64) recheck_kernel(const float* __restrict__ X,
                                                     const float* __restrict__ E,
                                                     const float* __restrict__ enorm,
                                                     const int* __restrict__ cnt,
                                                     const int* __restrict__ list,
                                                     float* __restrict__ out) {
  __shared__ float fsh[64];
  const int lane = threadIdx.x;
  const int n = *cnt;
  for (int ii = blockIdx.x; ii < n; ii += gridDim.x) {
    const int row = list[ii];
    const int b = row >> 12, h = (row >> 6) & 63, w = row & 63;
    fsh[lane] = X[((size_t)b * D + lane) * HW + h * 64 + w];
    __syncthreads();
    float best = 3.4e38f; int bidx = 0;
    for (int j = 0; j < 16; ++j) {
      const int k = lane + j * 64;           // ascending per lane
      const float* __restrict__ e = E + k * D;
      float a0 = 0.f, a1 = 0.f, a2 = 0.f, a3 = 0.f;
#pragma unroll
      for (int c = 0; c < D; c += 4) {
        a0 = fmaf(fsh[c + 0], e[c + 0], a0);
        a1 = fmaf(fsh[c + 1], e[c + 1], a1);
        a2 = fmaf(fsh[c + 2], e[c + 2], a2);
        a3 = fmaf(fsh[c + 3], e[c + 3], a3);
      }
      const float s = enorm[k] - 2.0f * ((a0 + a1) + (a2 + a3));
      if (s < best) { best = s; bidx = k; }
    }
#pragma unroll
    for (int m = 1; m < 64; m <<= 1) {
      const float ob = __shfl_xor(best, m, 64);
      const int   oi = __shfl_xor(bidx, m, 64);
      if (ob < best || (ob == best && oi < bidx)) { best = ob; bidx = oi; }
    }
    const float q = E[bidx * D + lane];
    float* __restrict__ ql = out + 2 * QSZ;
    ql[(size_t)row * D + lane] = q;
    out[((size_t)b * D + lane) * HW + h * 64 + w] = q;
    __syncthreads();
  }
}

// ---------------------------------------------------------------------------
// fallback (R1 kernels) if ws_size is too small for the bf16 tables
// ---------------------------------------------------------------------------
__global__ void __launch_bounds__(64) enorm_kernel(const float* __restrict__ E,
                                                   float* __restrict__ enorm) {
  const int k = blockIdx.x, c = threadIdx.x;
  float v = E[k * D + c];
  float s = v * v;
#pragma unroll
  for (int off = 32; off; off >>= 1) s += __shfl_down(s, off, 64);
  if (c == 0) enorm[k] = s;
}

__global__ void __launch_bounds__(256) vq_kernel(const float* __restrict__ X,
                                                 const float* __restrict__ E,
                                                 const float* __restrict__ enorm,
                                                 float* __restrict__ out) {
  const int bh = blockIdx.x, b = bh >> 6, h = bh & 63;
  const int tid = threadIdx.x, wave = tid >> 6, lane = tid & 63;
  const float* __restrict__ xbase = X + (size_t)b * (D * HW) + h * 64;
  float f[D];
#pragma unroll
  for (int c = 0; c < D; ++c) f[c] = xbase[c * HW + lane];
  float best = 3.4e38f; int bidx = 0;
  const int k0 = wave * (KC / 4);
  for (int k = k0; k < k0 + (KC / 4); ++k) {
    const float* __restrict__ e = E + k * D;
    float a0 = 0.f, a1 = 0.f, a2 = 0.f, a3 = 0.f;
#pragma unroll
    for (int c = 0; c < D; c += 4) {
      a0 = fmaf(f[c + 0], e[c + 0], a0);
      a1 = fmaf(f[c + 1], e[c + 1], a1);
      a2 = fmaf(f[c + 2], e[c + 2], a2);
      a3 = fmaf(f[c + 3], e[c + 3], a3);
    }
    const float score = enorm[k] - 2.0f * ((a0 + a1) + (a2 + a3));
    if (score < best) { best = score; bidx = k; }
  }
  __shared__ float sc_s[4][64]; __shared__ int id_s[4][64];
  __shared__ int idx_s[64]; __shared__ float tile[64 * 65]; __shared__ float eq[64 * 65];
  sc_s[wave][lane] = best; id_s[wave][lane] = bidx;
  if (wave == 0) {
#pragma unroll
    for (int c = 0; c < D; ++c) tile[c * 65 + lane] = f[c];
  }
  __syncthreads();
  if (tid < 64) {
    float bs = sc_s[0][tid]; int bi = id_s[0][tid];
#pragma unroll
    for (int wv = 1; wv < 4; ++wv) {
      if (sc_s[wv][tid] < bs) { bs = sc_s[wv][tid]; bi = id_s[wv][tid]; }
    }
    idx_s[tid] = bi;
  }
  __syncthreads();
  float* __restrict__ qout = out;
  float* __restrict__ lat = out + QSZ;
  float* __restrict__ ql = out + 2 * QSZ;
  const size_t n0 = (size_t)bh * 64;
#pragma unroll
  for (int i = 0; i < 16; ++i) {
    const int e_ = i * 256 + tid, w = e_ >> 6, c = e_ & 63;
    const float q = E[idx_s[w] * D + c];
    eq[w * 65 + c] = q;
    ql[(n0 + w) * D + c] = q;
    lat[(n0 + w) * D + c] = tile[c * 65 + w];
  }
  __syncthreads();
  float* __restrict__ qb = qout + (size_t)b * (D * HW) + h * 64;
#pragma unroll
  for (int i = 0; i < 16; ++i) {
    const int e_ = i * 256 + tid, c = e_ >> 6, w = e_ & 63;
    qb[c * HW + w] = eq[w * 65 + c];
  }
}

extern "C" void kernel_launch(void* const* d_in, const int* in_sizes, int n_in,
                              void* d_out, int out_size, void* d_ws, size_t ws_size,
                              hipStream_t stream) {
  const float* X = (const float*)d_in[0];
  const float* E = (const float*)d_in[1];
  float* out = (float*)d_out;
  char* ws = (char*)d_ws;

  if (ws_size >= WS_NEED) {
    float* enorm = (float*)(ws + WS_ENORM);
    unsigned short* Ehi = (unsigned short*)(ws + WS_EHI);
    unsigned short* Elo = (unsigned short*)(ws + WS_ELO);
    int* cnt  = (int*)(ws + WS_CNT);
    int* list = (int*)(ws + WS_LIST);
    prep_kernel<<<KC, 64, 0, stream>>>(E, enorm, Ehi, Elo, cnt);
    vq_mfma_kernel<<<256, 256, 0, stream>>>(X, E, enorm, Ehi, Elo, out, cnt, list);
    recheck_kernel<<<512, 64, 0, stream>>>(X, E, enorm, cnt, list, out);
  } else {
    float* enorm = (float*)ws;
    enorm_kernel<<<KC, 64, 0, stream>>>(E, enorm);
    vq_kernel<<<1024, 256, 0, stream>>>(X, E, enorm, out);
  }
}